// Round 16
// baseline (418.705 us; speedup 1.0000x reference)
//
#include <hip/hip_runtime.h>
#include <math.h>

// Full-fidelity emulation of the reference as run by jax-rocm EAGERLY on this
// GPU (x64 on): all f64 transcendentals are __ocml_*_f64 == this kernel's
// exp()/log(). Both stages are inexact because jax lowers exp2(z) ->
// exp(RN(z*RN(ln2))) -- reproduced bit-for-bit.
//
// R16 == R13 verbatim (best proven: 414.5us, absmax 0).
// R14/R15 post-mortem: the two-kernel split via d_ws failed twice with an
// IDENTICAL deterministic error signature (absmax 468/1.0) both with plain
// stores and with device-scope atomics -- refuting the coherence-race
// explanation and pointing at a harness-level d_ws interaction (re-poison /
// graph-capture semantics) that cannot be debugged from here. Split
// abandoned; reverting to the proven fused kernel.
//
// Cumulative proven configuration:
//  * Persistent 1024x256 grid, per-block tables (hidden under loads),
//    grid-stride over 256-value tiles, no steady-state barriers.
//  * Depth-2 prefetch, compile-time buffer roles (R13: -4.8us): pack(cur) ->
//    sched_barrier -> issue loads(t+2 into cur buffer) -> f64 chain ->
//    store(t). Loads issued a full iteration ahead -> ~100% in-flight duty.
//  * NT loads + NT stores (R9: removing NT = +15us).
//  * Butterfly 8x8 nibble transpose pack/store (R10/R12 proof), LDS LUT
//    expansion.
//  * Encode shortcuts (absmax==0 ten passing rounds):
//    - mantissa!=0 -> floor(log(a)/LN2) == E exactly; subnormal -> clip ==
//      -126; mantissa==0 (exact pow2) -> rare verbatim ocml log() path.
//    - mant = M + e, |e| <~ 1e-8: for sc > ctz(M), floor(mant*Lm[sc]) ==
//      M>>sc exactly -> parity is bit sc of M; only sc <= ctz(M) (incl. the
//      pow2 M=0 "W-1 garbage" case) runs the original f64 mul+floor step.

#define LN2C 0x1.62e42fefa39efp-1  // RN(ln2), XLA's folded log(2)

typedef unsigned int u32x4 __attribute__((ext_vector_type(4)));

__device__ __forceinline__ uint32_t nib_transpose8(uint32_t x, int p) {
  // Transpose the 8x8 nibble matrix held across the 8 lanes of a group
  // (row = lane p, col = nibble slot k). Involution.
  uint32_t r;
  r = __shfl_xor(x, 1);
  x = (p & 1) ? ((x & 0xF0F0F0F0u) | ((r >> 4) & 0x0F0F0F0Fu))
              : ((x & 0x0F0F0F0Fu) | ((r << 4) & 0xF0F0F0F0u));
  r = __shfl_xor(x, 2);
  x = (p & 2) ? ((x & 0xFF00FF00u) | ((r >> 8) & 0x00FF00FFu))
              : ((x & 0x00FF00FFu) | ((r << 8) & 0xFF00FF00u));
  r = __shfl_xor(x, 4);
  x = (p & 4) ? ((x & 0xFFFF0000u) | ((r >> 16) & 0x0000FFFFu))
              : ((x & 0x0000FFFFu) | ((r << 16) & 0xFFFF0000u));
  return x;
}

__device__ __forceinline__ uint32_t nib_reverse(uint32_t x) {
  uint32_t b = __builtin_bswap32(x);
  return ((b >> 4) & 0x0F0F0F0Fu) | ((b << 4) & 0xF0F0F0F0u);
}

__device__ __forceinline__ void load_tile(const u32x4* __restrict__ in,
                                          int cb, int n_chunks,
                                          u32x4 (&B)[8]) {
#pragma unroll
  for (int i = 0; i < 8; ++i) {
    int g = cb + i * 64;
    u32x4 b = {0u, 0u, 0u, 0u};
    if (g < n_chunks) b = __builtin_nontemporal_load(&in[g]);
    B[i] = b;
  }
}

__device__ __forceinline__ uint32_t pack_tile(const u32x4 (&B)[8], int kp) {
  // Lane-local nibble accumulation + 8x8 butterfly + nibble-reverse ->
  // this lane's value word (v = vwave + kp*8 + (lane>>3)). See R10 proof.
  uint32_t X = 0u;
#pragma unroll
  for (int i = 0; i < 8; ++i) {
    u32x4 b = B[i];
    uint32_t nib = (((b.x >> 23) & 1u) << 3) | (((b.y >> 23) & 1u) << 2) |
                   (((b.z >> 23) & 1u) << 1) | ((b.w >> 23) & 1u);
    X |= nib << (4 * i);
  }
  return nib_reverse(nib_transpose8(X, kp));
}

__global__ __launch_bounds__(256, 4) void spike_gelu_kernel(
    const u32x4* __restrict__ in, u32x4* __restrict__ out,
    int n_vals, int n_tiles) {
#pragma clang fp contract(off)
  const double LN2 = LN2C;
  // Tables (exact ocml-call replicas of the reference's constant arrays):
  __shared__ double Wdec[8];     // decode exponent weights exp2emu(7..0)
  __shared__ double Lms[23];     // ladder scales exp2emu(0..-22)
  __shared__ double E1t[256];    // ordered Wdec sum -> exp((e_c-127)*LN2)
  __shared__ double Vdec[23];    // decode fraction weights exp2emu(-1..-23)
  __shared__ double P2t[254];    // encode exp(-e0*LN2), e0 in [-126,127]
  __shared__ uint32_t etab[256]; // 8-step exponent floor-ladder per eb
  __shared__ u32x4 lut16[16];    // nibble -> 4 pulse floats (x=bit3..w=bit0)

  const int tid = threadIdx.x;
  const int lane = tid & 63;
  const int kp = lane & 7;   // position within 8-lane group
  const int wid = tid >> 6;  // 0..3
  const int n_chunks = n_vals * 8;
  const int tstep = gridDim.x;  // grid-stride over 256-value tiles
  const int laneoff = wid * 512 + lane;

  int tile = blockIdx.x;

  // ---- prologue: tile-0 loads in flight under the table build -------------
  u32x4 A[8], Bb[8];
  load_tile(in, tile * 2048 + laneoff, n_chunks, A);

  // ---- table stage 1 ------------------------------------------------------
  if (tid < 8) Wdec[tid] = exp((double)(7 - tid) * LN2);
  if (tid >= 31 && tid < 54) Lms[tid - 31] = exp((double)(31 - tid) * LN2);
  __syncthreads();
  // ---- table stage 2 (reference op order) ---------------------------------
  if (tid == 0) {
    E1t[0] = exp(-126.0 * LN2);  // subnormal-branch scale (e_c==0)
  } else {
    double e_c = 0.0;
#pragma unroll
    for (int j = 0; j < 8; ++j)   // ascending-j einsum accumulation, verbatim
      if ((tid >> (7 - j)) & 1) e_c = e_c + Wdec[j];
    E1t[tid] = exp((e_c - 127.0) * LN2);
  }
  if (tid < 23) Vdec[tid] = exp((double)(-1 - tid) * LN2);
  if (tid < 254) P2t[tid] = exp((double)(126 - tid) * LN2);  // exp(-e0*LN2)
  if (tid < 16) {
    u32x4 e;
    e.x = ((tid >> 3) & 1u) * 0x3F800000u;
    e.y = ((tid >> 2) & 1u) * 0x3F800000u;
    e.z = ((tid >> 1) & 1u) * 0x3F800000u;
    e.w = (tid & 1u) * 0x3F800000u;
    lut16[tid] = e;
  }
  if (tid >= 1 && tid < 255) {  // exponent-bit ladder, original formula
    double eb = (double)tid;
    uint32_t r = 0;
#pragma unroll
    for (int sc = 7; sc >= 0; --sc) {
      double f = floor(eb * Lms[sc]);
      double md = f - 2.0 * floor(0.5 * f);
      r |= ((uint32_t)md) << (23 + sc);
    }
    etab[tid] = r;
  } else if (tid == 255 || tid == 0) {
    etab[tid] = 0u;  // hygiene, never read
  }
  __syncthreads();  // tables ready; no further block-wide coupling

  // ---- prologue: tile-1 loads (prefetch depth 2 established) --------------
  if (tile + tstep < n_tiles)
    load_tile(in, (tile + tstep) * 2048 + laneoff, n_chunks, Bb);

  // chain + store, factored (compile-time everything; see R10 proof for the
  // store-side inverse butterfly + LUT expansion)
  auto chain_store = [&](uint32_t w0, int t) {
    const int vwave = t * 256 + wid * 64;
    const int v0 = vwave + kp * 8 + (lane >> 3);
    const bool ok0 = v0 < n_vals;

    // DECODE
    double f0 = 0.0;
#pragma unroll
    for (int j = 0; j < 23; ++j)
      if ((w0 >> (22 - j)) & 1u) f0 = f0 + Vdec[j];
    uint32_t ei0 = (w0 >> 23) & 0xFFu;
    double sg0 = (w0 >> 31) ? -1.0 : 1.0;
    double fa0 = ei0 ? (1.0 + f0) : f0;
    double x0 = (sg0 * E1t[ei0]) * fa0;

    // f64 GELU, exp-form logistic, ocml exp
    double t0 = 1.702 * x0;
    double e0v = exp(-t0);
    double s0 = 1.0 / (1.0 + e0v);
    double y0 = x0 * s0;
    float yf0 = (float)y0;   // astype(float32): RN
    double yd0 = (double)yf0;

    // ENCODE
    double a0 = fabs(yd0);
    uint32_t yb0 = __float_as_uint(yf0);
    uint32_t Ef0 = (yb0 >> 23) & 0xFFu;
    uint32_t mbf0 = yb0 & 0x7FFFFFu;
    int e00 = (Ef0 == 0u) ? -126 : (int)Ef0 - 127;
    bool pw0 = ok0 && (a0 > 0.0) && (Ef0 != 0u) && (mbf0 == 0u);
    if (__builtin_expect(pw0, 0)) {  // exact pow2: ocml log boundary
      double e0 = floor(log(a0) / LN2);
      e00 = (int)fmin(fmax(e0, -126.0), 127.0);
    }
    double p20 = P2t[e00 + 126];
    double m10 = a0 * p20;               // RN: may be W' +- eps
    double mant0 = (m10 - 1.0) * 8388608.0;  // Sterbenz-exact, exact scale
    int M0 = (int)rint(mant0);
    uint32_t mb0 = ((uint32_t)M0) & 0x7FFFFFu;
    int T0 = M0 ? __builtin_ctz((uint32_t)M0) : 23;
    int L0 = T0 < 22 ? T0 : 22;
    for (int sc = 0; sc <= L0; ++sc) {   // boundary scs: original f64 math
      double f = floor(mant0 * Lms[sc]);
      mb0 = (mb0 & ~(1u << sc)) | (((uint32_t)(((int)f) & 1)) << sc);
    }
    uint32_t ob0 = (yb0 & 0x80000000u) | etab[e00 + 127] | mb0;
    ob0 = (ok0 && a0 > 0.0) ? ob0 : 0u;

    // store: inverse butterfly + LUT expansion, NT
    uint32_t Z = nib_transpose8(nib_reverse(ob0), kp);
    const int cb = t * 2048 + laneoff;
#pragma unroll
    for (int i = 0; i < 8; ++i) {
      int g = cb + i * 64;
      if (g < n_chunks) {
        u32x4 o = lut16[(Z >> (4 * i)) & 0xFu];
        __builtin_nontemporal_store(o, &out[g]);
      }
    }
  };

  // ---- steady-state: unrolled x2 (A-phase / B-phase), depth-2 prefetch ----
  for (;;) {
    // A-phase: cur=A holds tile; B holds tile+tstep (in flight or arrived)
    {
      uint32_t w0 = pack_tile(A, kp);          // waits only A's (oldest) loads
      __builtin_amdgcn_sched_barrier(0);       // don't hoist refill above pack
      int t2 = tile + 2 * tstep;
      if (t2 < n_tiles) load_tile(in, t2 * 2048 + laneoff, n_chunks, A);
      chain_store(w0, tile);
    }
    if (tile + tstep >= n_tiles) break;

    // B-phase: cur=B holds tile+tstep; A holds tile+2*tstep (in flight)
    {
      int tb = tile + tstep;
      uint32_t w0 = pack_tile(Bb, kp);
      __builtin_amdgcn_sched_barrier(0);
      int t3 = tb + 2 * tstep;
      if (t3 < n_tiles) load_tile(in, t3 * 2048 + laneoff, n_chunks, Bb);
      chain_store(w0, tb);
    }
    tile += 2 * tstep;
    if (tile >= n_tiles) break;
  }
}

extern "C" void kernel_launch(void* const* d_in, const int* in_sizes, int n_in,
                              void* d_out, int out_size, void* d_ws, size_t ws_size,
                              hipStream_t stream) {
  int n_vals = in_sizes[0] / 32;
  int n_tiles = (n_vals + 255) / 256;
  int grid = n_tiles < 1024 ? n_tiles : 1024;
  spike_gelu_kernel<<<grid, 256, 0, stream>>>(
      (const u32x4*)d_in[0], (u32x4*)d_out, n_vals, n_tiles);
}